// Round 9
// baseline (529.643 us; speedup 1.0000x reference)
//
#include <hip/hip_runtime.h>

#define ALPHA_F 0.1f
#define EPS_F   1e-5f

typedef float    f32x4 __attribute__((ext_vector_type(4)));
typedef _Float16 h16x8 __attribute__((ext_vector_type(8)));
typedef unsigned short u16x8 __attribute__((ext_vector_type(8)));

// padded count per node: self-loop + edges, rounded up to multiple of 8
__device__ __forceinline__ int pad_cnt(int d) { return (d + 8) & ~7; }

// ---------------------------------------------------------------------------
// W [K x 128] fp32 -> Wt [128 x K] fp16 (transposed)
// ---------------------------------------------------------------------------
__global__ void convert_wt16(const float* __restrict__ W,
                             _Float16* __restrict__ Wt, int K)
{
    int idx = blockIdx.x * 256 + threadIdx.x;
    if (idx < K * 128) {
        int k = idx >> 7, n = idx & 127;
        Wt[(size_t)n * K + k] = (_Float16)W[idx];
    }
}

// ---------------------------------------------------------------------------
// out[M,128] = BN( act(A[M,K] @ W + bias) ), fp16 MFMA, fp32 accumulate.
// BARRIER-FREE streaming: no LDS. Each wave owns 16 rows; B-fragments are
// loaded per k-step straight from L2-resident Wt (128 KB max). Double-
// buffered registers across the 64-wide k0 loop keep ~20 loads in flight;
// with no __syncthreads there is no vmcnt(0) drain anywhere in the loop.
// ---------------------------------------------------------------------------
template<bool A_HALF, bool OUT_HALF>
__global__ __launch_bounds__(256) void gemm_mfma_bn(
    const void* __restrict__ Av,
    const _Float16* __restrict__ Wt,   // [128][K] fp16
    const float* __restrict__ bias,
    const float* __restrict__ gamma, const float* __restrict__ beta,
    const float* __restrict__ mean,  const float* __restrict__ var,
    void* __restrict__ outv, int M, int K, int do_relu)
{
    const int t   = threadIdx.x;       // 0..255
    const int w   = t >> 6;            // wave 0..3
    const int l   = t & 63;
    const int l15 = l & 15;
    const int lk  = l >> 4;            // 0..3
    const int bm  = blockIdx.x * 64;
    const int r   = bm + w * 16 + l15; // this lane's A row
    const size_t arow = (size_t)((r < M) ? r : 0) * K;

    const float*    Af = (const float*)Av    + arow;
    const _Float16* Ah = (const _Float16*)Av + arow;

    f32x4 acc[8];
#pragma unroll
    for (int f = 0; f < 8; ++f) acc[f] = (f32x4){0.f, 0.f, 0.f, 0.f};

    h16x8 aC[2], aN[2];
    h16x8 bC[2][8], bN[2][8];

    auto loadA = [&](int k0, h16x8* dst) {
#pragma unroll
        for (int s = 0; s < 2; ++s) {
            if (A_HALF) {
                dst[s] = *(const h16x8*)(Ah + k0 + s * 32 + lk * 8);
            } else {
                f32x4 v0 = *(const f32x4*)(Af + k0 + s * 32 + lk * 8);
                f32x4 v1 = *(const f32x4*)(Af + k0 + s * 32 + lk * 8 + 4);
                h16x8 h;
#pragma unroll
                for (int j = 0; j < 4; ++j) {
                    h[j]     = (_Float16)v0[j];
                    h[4 + j] = (_Float16)v1[j];
                }
                dst[s] = h;
            }
        }
    };
    auto loadB = [&](int k0, h16x8 (*dst)[8]) {
#pragma unroll
        for (int s = 0; s < 2; ++s)
#pragma unroll
            for (int f = 0; f < 8; ++f)
                dst[s][f] = *(const h16x8*)(Wt + (size_t)(f * 16 + l15) * K
                                               + k0 + s * 32 + lk * 8);
    };

    loadA(0, aC);
    loadB(0, bC);

    for (int k0 = 0; k0 < K; k0 += 64) {
        if (k0 + 64 < K) {            // issue next block's loads first
            loadA(k0 + 64, aN);
            loadB(k0 + 64, bN);
        }
#pragma unroll
        for (int s = 0; s < 2; ++s)
#pragma unroll
            for (int f = 0; f < 8; ++f)
                acc[f] = __builtin_amdgcn_mfma_f32_16x16x32_f16(
                    aC[s], bC[s][f], acc[f], 0, 0, 0);
#pragma unroll
        for (int s = 0; s < 2; ++s) {
            aC[s] = aN[s];
#pragma unroll
            for (int f = 0; f < 8; ++f) bC[s][f] = bN[s][f];
        }
    }

    // epilogue: bias -> (relu) -> BN.  D: col=l15, row=lk*4+rr
#pragma unroll
    for (int f = 0; f < 8; ++f) {
        int col  = f * 16 + l15;
        float s  = gamma[col] * rsqrtf(var[col] + EPS_F);
        float sh = beta[col] - mean[col] * s;
        float bb = bias[col];
#pragma unroll
        for (int rr = 0; rr < 4; ++rr) {
            int rg = bm + w * 16 + lk * 4 + rr;
            if (rg < M) {
                float v = acc[f][rr] + bb;
                if (do_relu) v = fmaxf(v, 0.f);
                v = v * s + sh;
                if (OUT_HALF) ((_Float16*)outv)[(size_t)rg * 128 + col] = (_Float16)v;
                else          ((float*)outv)[(size_t)rg * 128 + col]    = v;
            }
        }
    }
}

// ---------------------------------------------------------------------------
// Graph preprocessing (per launch)
// ---------------------------------------------------------------------------
__global__ void count_deg(const int* __restrict__ dst, int E, int* __restrict__ deg)
{
    int e = blockIdx.x * 256 + threadIdx.x;
    if (e < E) atomicAdd(&deg[dst[e]], 1);
}

__global__ __launch_bounds__(256) void scan_block_sums(
    const int* __restrict__ deg, int* __restrict__ bsum, int N)
{
    __shared__ int sh[256];
    const int t  = threadIdx.x;
    const int i0 = blockIdx.x * 1024 + t * 4;
    int s = 0;
    if (i0 + 3 < N) {
        int4 d4 = *(const int4*)(deg + i0);
        s = pad_cnt(d4.x) + pad_cnt(d4.y) + pad_cnt(d4.z) + pad_cnt(d4.w);
    } else {
#pragma unroll
        for (int j = 0; j < 4; ++j)
            if (i0 + j < N) s += pad_cnt(deg[i0 + j]);
    }
    sh[t] = s;
    __syncthreads();
#pragma unroll
    for (int d = 128; d > 0; d >>= 1) {
        if (t < d) sh[t] += sh[t + d];
        __syncthreads();
    }
    if (t == 0) bsum[blockIdx.x] = sh[0];
}

__global__ __launch_bounds__(256) void scan_offsets(
    const int* __restrict__ deg, const int* __restrict__ bsum,
    int* __restrict__ offs, int* __restrict__ cursor, int N, int B)
{
    __shared__ int sh[256];
    __shared__ int sbase;
    const int b = blockIdx.x, t = threadIdx.x;

    int v = (t < b && t < B) ? bsum[t] : 0;   // B <= 256
    sh[t] = v;
    __syncthreads();
#pragma unroll
    for (int d = 128; d > 0; d >>= 1) {
        if (t < d) sh[t] += sh[t + d];
        __syncthreads();
    }
    if (t == 0) sbase = sh[0];
    __syncthreads();

    const int i0 = b * 1024 + t * 4;
    int c[4], s = 0;
#pragma unroll
    for (int j = 0; j < 4; ++j) {
        int i = i0 + j;
        c[j] = (i < N) ? pad_cnt(deg[i]) : 0;
        s += c[j];
    }
    sh[t] = s;
    __syncthreads();
    for (int d = 1; d < 256; d <<= 1) {
        int o = (t >= d) ? sh[t - d] : 0;
        __syncthreads();
        sh[t] += o;
        __syncthreads();
    }
    int run = sbase + sh[t] - s;   // exclusive prefix
#pragma unroll
    for (int j = 0; j < 4; ++j) {
        int i = i0 + j;
        if (i < N) {
            offs[i]   = run;
            cursor[i] = run;
            run += c[j];
        }
    }
    if (b == B - 1 && t == 255) offs[N] = run;
}

__global__ void compute_dinv(const int* __restrict__ deg, float* __restrict__ dinv, int N)
{
    int i = blockIdx.x * 256 + threadIdx.x;
    if (i < N) dinv[i] = rsqrtf((float)(deg[i] + 1));  // +1 self loop
}

__global__ void scatter_csr(const int* __restrict__ src, const int* __restrict__ dst,
                            int E, const float* __restrict__ dinv,
                            int* __restrict__ cursor,
                            int* __restrict__ csr_src, float* __restrict__ csr_val)
{
    int e = blockIdx.x * 256 + threadIdx.x;
    if (e < E) {
        int s = src[e], d = dst[e];
        int pos = atomicAdd(&cursor[d], 1);
        csr_src[pos] = s;
        csr_val[pos] = dinv[s] * dinv[d];
    }
}

__global__ void fill_self_pad(const int* __restrict__ offs, const int* __restrict__ deg,
                              const float* __restrict__ dinv,
                              int* __restrict__ csr_src, float* __restrict__ csr_val, int N)
{
    int i = blockIdx.x * 256 + threadIdx.x;
    if (i < N) {
        int base = offs[i], d = deg[i], end = offs[i + 1];
        float di = dinv[i];
        csr_src[base + d] = i;
        csr_val[base + d] = di * di;
        for (int p = base + d + 1; p < end; ++p) {
            csr_src[p] = i;
            csr_val[p] = 0.f;
        }
    }
}

// 32 safe entries past offs[N] so the step kernel's prefetch can overrun
__global__ void pad_csr_tail(const int* __restrict__ offs, int N,
                             int* __restrict__ csr_src, float* __restrict__ csr_val)
{
    int base = offs[N];
    int j = threadIdx.x;   // 32 threads, 1 block
    csr_src[base + j] = 0;
    csr_val[base + j] = 0.f;
}

// ---------------------------------------------------------------------------
// One APPNP step (fp16 features): nxt = (1-a)*(A_hat @ cur) + a*h0.
// One wave per node; four 16-lane groups, 8 feats (16B) per lane.
// Depth-3 software pipeline: csr metadata loaded 2 windows ahead, gathers
// issued 1 window ahead -> no serial csr->gather latency in the loop body.
// ---------------------------------------------------------------------------
__global__ __launch_bounds__(256) void appnp_step(
    const _Float16* __restrict__ cur, const _Float16* __restrict__ h0,
    const int* __restrict__ offs,
    const int* __restrict__ csr_src, const float* __restrict__ csr_val,
    _Float16* __restrict__ nxt, float* __restrict__ fout, int N)
{
    int wv = (int)((blockIdx.x * 256u + threadIdx.x) >> 6);
    if (wv >= N) return;
    const int i    = __builtin_amdgcn_readfirstlane(wv);
    const int lane = (int)(threadIdx.x & 63u);
    const int g    = lane >> 4;          // group 0..3
    const int fl   = (lane & 15) * 8;    // feature offset

    int e   = offs[i];
    int end = offs[i + 1];

    f32x4 accL = (f32x4){0.f, 0.f, 0.f, 0.f};
    f32x4 accH = (f32x4){0.f, 0.f, 0.f, 0.f};

    // window 0: csr + gathers
    int   iA0 = csr_src[e + g],     iB0 = csr_src[e + 4 + g];
    float wA0 = csr_val[e + g],     wB0 = csr_val[e + 4 + g];
    h16x8 vA  = *(const h16x8*)(cur + (size_t)iA0 * 128 + fl);
    h16x8 vB  = *(const h16x8*)(cur + (size_t)iB0 * 128 + fl);
    // window 1: csr only (tail-padded, always safe)
    int   iA1 = csr_src[e + 8 + g],  iB1 = csr_src[e + 12 + g];
    float wA1 = csr_val[e + 8 + g],  wB1 = csr_val[e + 12 + g];

    for (; e + 8 < end; e += 8) {
        // csr(W+2)
        int   iA2 = csr_src[e + 16 + g], iB2 = csr_src[e + 20 + g];
        float wA2 = csr_val[e + 16 + g], wB2 = csr_val[e + 20 + g];
        // gathers(W+1) — indices loaded a full iteration ago
        h16x8 vA1 = *(const h16x8*)(cur + (size_t)iA1 * 128 + fl);
        h16x8 vB1 = *(const h16x8*)(cur + (size_t)iB1 * 128 + fl);
        // FMA window W — data loaded a full iteration ago
#pragma unroll
        for (int j = 0; j < 4; ++j) {
            accL[j] = fmaf(wA0, (float)vA[j],     accL[j]);
            accH[j] = fmaf(wA0, (float)vA[4 + j], accH[j]);
            accL[j] = fmaf(wB0, (float)vB[j],     accL[j]);
            accH[j] = fmaf(wB0, (float)vB[4 + j], accH[j]);
        }
        // rotate
        vA = vA1; vB = vB1; wA0 = wA1; wB0 = wB1;
        iA1 = iA2; iB1 = iB2; wA1 = wA2; wB1 = wB2;
    }
    // tail window
#pragma unroll
    for (int j = 0; j < 4; ++j) {
        accL[j] = fmaf(wA0, (float)vA[j],     accL[j]);
        accH[j] = fmaf(wA0, (float)vA[4 + j], accH[j]);
        accL[j] = fmaf(wB0, (float)vB[j],     accL[j]);
        accH[j] = fmaf(wB0, (float)vB[4 + j], accH[j]);
    }

    // combine the four group partial sums (butterfly)
#pragma unroll
    for (int j = 0; j < 4; ++j) {
        accL[j] += __shfl_xor(accL[j], 16);
        accL[j] += __shfl_xor(accL[j], 32);
        accH[j] += __shfl_xor(accH[j], 16);
        accH[j] += __shfl_xor(accH[j], 32);
    }

    if (lane < 16) {
        h16x8 hv = *(const h16x8*)(h0 + (size_t)i * 128 + fl);
        float o[8];
#pragma unroll
        for (int j = 0; j < 4; ++j) {
            o[j]     = ALPHA_F * (float)hv[j]     + (1.f - ALPHA_F) * accL[j];
            o[4 + j] = ALPHA_F * (float)hv[4 + j] + (1.f - ALPHA_F) * accH[j];
        }
        if (fout) {
            f32x4 o0, o1;
#pragma unroll
            for (int j = 0; j < 4; ++j) { o0[j] = o[j]; o1[j] = o[4 + j]; }
            *(f32x4*)(fout + (size_t)i * 128 + fl)     = o0;
            *(f32x4*)(fout + (size_t)i * 128 + fl + 4) = o1;
        } else {
            h16x8 o16;
#pragma unroll
            for (int j = 0; j < 8; ++j) o16[j] = (_Float16)o[j];
            *(h16x8*)(nxt + (size_t)i * 128 + fl) = o16;
        }
    }
}

// ---------------------------------------------------------------------------
static inline size_t align_up(size_t x) { return (x + 255) & ~(size_t)255; }

extern "C" void kernel_launch(void* const* d_in, const int* in_sizes, int n_in,
                              void* d_out, int out_size, void* d_ws, size_t ws_size,
                              hipStream_t stream)
{
    const float* x   = (const float*)d_in[0];
    const int*   ei  = (const int*)d_in[1];
    const float* W1  = (const float*)d_in[2];
    const float* b1  = (const float*)d_in[3];
    const float* g1  = (const float*)d_in[4];
    const float* be1 = (const float*)d_in[5];
    const float* m1  = (const float*)d_in[6];
    const float* v1  = (const float*)d_in[7];
    const float* W2  = (const float*)d_in[8];
    const float* b2  = (const float*)d_in[9];
    const float* g2  = (const float*)d_in[10];
    const float* be2 = (const float*)d_in[11];
    const float* m2  = (const float*)d_in[12];
    const float* v2  = (const float*)d_in[13];

    const int N = in_sizes[0] / 512;   // 50000
    const int E = in_sizes[1] / 2;     // 800000
    const int* src = ei;
    const int* dst = ei + E;
    const int CSR_CAP = E + 8 * N + 64;
    const int NB = (N + 1023) / 1024;  // 49

    char* ws = (char*)d_ws;
    size_t off = 0;
    _Float16* hAh = (_Float16*)(ws + off); off += align_up((size_t)N * 128 * 2);
    _Float16* h0h = (_Float16*)(ws + off); off += align_up((size_t)N * 128 * 2);
    _Float16* p0  = (_Float16*)(ws + off); off += align_up((size_t)N * 128 * 2);
    _Float16* p1  = (_Float16*)(ws + off); off += align_up((size_t)N * 128 * 2);
    int*    deg  = (int*)(ws + off);    off += align_up((size_t)N * 4);
    float*  dinv = (float*)(ws + off);  off += align_up((size_t)N * 4);
    int*    offs = (int*)(ws + off);    off += align_up((size_t)(N + 1) * 4);
    int*    curs = (int*)(ws + off);    off += align_up((size_t)N * 4);
    int*    bsum = (int*)(ws + off);    off += align_up((size_t)256 * 4);
    int*    csrs = (int*)(ws + off);    off += align_up((size_t)CSR_CAP * 4);
    float*  csrv = (float*)(ws + off);  off += align_up((size_t)CSR_CAP * 4);
    _Float16* w1t = (_Float16*)(ws + off); off += align_up((size_t)512 * 128 * 2);
    _Float16* w2t = (_Float16*)(ws + off); off += align_up((size_t)128 * 128 * 2);

    // --- graph preprocessing ---
    hipMemsetAsync(deg, 0, (size_t)N * 4, stream);
    count_deg<<<(E + 255) / 256, 256, 0, stream>>>(dst, E, deg);
    scan_block_sums<<<NB, 256, 0, stream>>>(deg, bsum, N);
    scan_offsets<<<NB, 256, 0, stream>>>(deg, bsum, offs, curs, N, NB);
    compute_dinv<<<(N + 255) / 256, 256, 0, stream>>>(deg, dinv, N);
    scatter_csr<<<(E + 255) / 256, 256, 0, stream>>>(src, dst, E, dinv, curs, csrs, csrv);
    fill_self_pad<<<(N + 255) / 256, 256, 0, stream>>>(offs, deg, dinv, csrs, csrv, N);
    pad_csr_tail<<<1, 32, 0, stream>>>(offs, N, csrs, csrv);

    // --- weights -> transposed fp16 ---
    convert_wt16<<<(512 * 128 + 255) / 256, 256, 0, stream>>>(W1, w1t, 512);
    convert_wt16<<<(128 * 128 + 255) / 256, 256, 0, stream>>>(W2, w2t, 128);

    // --- MLP: hAh = BN1(relu(x@W1+b1)) fp16; h0h = BN2(hAh@W2+b2) fp16 ---
    gemm_mfma_bn<false, true><<<(N + 63) / 64, 256, 0, stream>>>(
        x, w1t, b1, g1, be1, m1, v1, hAh, N, 512, 1);
    gemm_mfma_bn<true, true><<<(N + 63) / 64, 256, 0, stream>>>(
        hAh, w2t, b2, g2, be2, m2, v2, h0h, N, 128, 0);

    // --- 10 propagation steps (fp16 ping-pong); step 10 writes fp32 d_out ---
    const _Float16* cur = h0h;
    for (int k = 0; k < 10; ++k) {
        _Float16* nxt = (k & 1) ? p1 : p0;
        float* fo = (k == 9) ? (float*)d_out : nullptr;
        appnp_step<<<(N + 3) / 4, 256, 0, stream>>>(
            cur, h0h, offs, csrs, csrv, nxt, fo, N);
        cur = nxt;
    }

    (void)n_in; (void)out_size; (void)ws_size;
}

// Round 10
// 500.953 us; speedup vs baseline: 1.0573x; 1.0573x over previous
//
#include <hip/hip_runtime.h>

#define ALPHA_F 0.1f
#define EPS_F   1e-5f

typedef float    f32x4 __attribute__((ext_vector_type(4)));
typedef _Float16 h16x8 __attribute__((ext_vector_type(8)));

// padded count per node: self-loop + edges, rounded up to multiple of 8
__device__ __forceinline__ int pad_cnt(int d) { return (d + 8) & ~7; }

// ---------------------------------------------------------------------------
// W [K x 128] fp32 -> Wt [128 x K] fp16 (transposed)
// ---------------------------------------------------------------------------
__global__ void convert_wt16(const float* __restrict__ W,
                             _Float16* __restrict__ Wt, int K)
{
    int idx = blockIdx.x * 256 + threadIdx.x;
    if (idx < K * 128) {
        int k = idx >> 7, n = idx & 127;
        Wt[(size_t)n * K + k] = (_Float16)W[idx];
    }
}

// ---------------------------------------------------------------------------
// out[M,128] = BN( act(A[M,K] @ W + bias) ), fp16 MFMA, fp32 accumulate.
// SPLIT-K x4: block = 16 rows, 4 waves; wave w computes K-slice
// [w*K/4,(w+1)*K/4) independently (no barriers in main loop), then one
// XOR-swizzled LDS reduction + BN epilogue. 3125 blocks = 12500 waves
// -> latency hidden by wave-level parallelism instead of intra-wave ILP.
// ---------------------------------------------------------------------------
template<bool A_HALF, bool OUT_HALF>
__global__ __launch_bounds__(256) void gemm_ksplit_bn(
    const void* __restrict__ Av,
    const _Float16* __restrict__ Wt,   // [128][K] fp16
    const float* __restrict__ bias,
    const float* __restrict__ gamma, const float* __restrict__ beta,
    const float* __restrict__ mean,  const float* __restrict__ var,
    void* __restrict__ outv, int M, int K, int do_relu)
{
    __shared__ f32x4 red[4][64][8];    // 32 KB, [wave][lane][swizzled frag]

    const int t   = threadIdx.x;       // 0..255
    const int w   = t >> 6;            // wave 0..3
    const int l   = t & 63;
    const int l15 = l & 15;
    const int lk  = l >> 4;            // 0..3
    const int bm  = blockIdx.x * 16;
    const int r   = bm + l15;          // this lane's A row
    const int kw  = K >> 2;            // K per wave
    const int kb  = w * kw;            // this wave's K base
    const int nch = kw >> 5;           // chunks of 32

    const size_t arow = (size_t)((r < M) ? r : 0) * K;
    const float*    Af = (const float*)Av    + arow + kb;
    const _Float16* Ah = (const _Float16*)Av + arow + kb;

    f32x4 acc[8];
#pragma unroll
    for (int f = 0; f < 8; ++f) acc[f] = (f32x4){0.f, 0.f, 0.f, 0.f};

    h16x8 aC, aN;
    h16x8 bC[8], bN[8];

    auto loadA = [&](int c, h16x8& dst) {
        if (A_HALF) {
            dst = *(const h16x8*)(Ah + c * 32 + lk * 8);
        } else {
            f32x4 v0 = *(const f32x4*)(Af + c * 32 + lk * 8);
            f32x4 v1 = *(const f32x4*)(Af + c * 32 + lk * 8 + 4);
            h16x8 h;
#pragma unroll
            for (int j = 0; j < 4; ++j) {
                h[j]     = (_Float16)v0[j];
                h[4 + j] = (_Float16)v1[j];
            }
            dst = h;
        }
    };
    auto loadB = [&](int c, h16x8* dst) {
#pragma unroll
        for (int f = 0; f < 8; ++f)
            dst[f] = *(const h16x8*)(Wt + (size_t)(f * 16 + l15) * K
                                        + kb + c * 32 + lk * 8);
    };

    loadA(0, aC);
    loadB(0, bC);

    for (int c = 0; c < nch; ++c) {
        if (c + 1 < nch) {             // issue next chunk's loads first
            loadA(c + 1, aN);
            loadB(c + 1, bN);
        }
#pragma unroll
        for (int f = 0; f < 8; ++f)
            acc[f] = __builtin_amdgcn_mfma_f32_16x16x32_f16(aC, bC[f], acc[f], 0, 0, 0);
        aC = aN;
#pragma unroll
        for (int f = 0; f < 8; ++f) bC[f] = bN[f];
    }

    // --- cross-wave K reduction via LDS (XOR slot swizzle spreads banks) ---
    const int sw = l & 7;
#pragma unroll
    for (int f = 0; f < 8; ++f) red[w][l][f ^ sw] = acc[f];
    __syncthreads();

    // wave w handles output frags 2w, 2w+1
#pragma unroll
    for (int j = 0; j < 2; ++j) {
        const int f = 2 * w + j;
        f32x4 v = red[0][l][f ^ sw];
        v += red[1][l][f ^ sw];
        v += red[2][l][f ^ sw];
        v += red[3][l][f ^ sw];

        const int col = f * 16 + l15;
        float s  = gamma[col] * rsqrtf(var[col] + EPS_F);
        float sh = beta[col] - mean[col] * s;
        float bb = bias[col];
#pragma unroll
        for (int rr = 0; rr < 4; ++rr) {
            int rg = bm + lk * 4 + rr;
            if (rg < M) {
                float o = v[rr] + bb;
                if (do_relu) o = fmaxf(o, 0.f);
                o = o * s + sh;
                if (OUT_HALF) ((_Float16*)outv)[(size_t)rg * 128 + col] = (_Float16)o;
                else          ((float*)outv)[(size_t)rg * 128 + col]    = o;
            }
        }
    }
}

// ---------------------------------------------------------------------------
// Graph preprocessing (per launch)
// ---------------------------------------------------------------------------
__global__ void count_deg(const int* __restrict__ dst, int E, int* __restrict__ deg)
{
    int e = blockIdx.x * 256 + threadIdx.x;
    if (e < E) atomicAdd(&deg[dst[e]], 1);
}

__global__ __launch_bounds__(256) void scan_block_sums(
    const int* __restrict__ deg, int* __restrict__ bsum, int N)
{
    __shared__ int sh[256];
    const int t  = threadIdx.x;
    const int i0 = blockIdx.x * 1024 + t * 4;
    int s = 0;
    if (i0 + 3 < N) {
        int4 d4 = *(const int4*)(deg + i0);
        s = pad_cnt(d4.x) + pad_cnt(d4.y) + pad_cnt(d4.z) + pad_cnt(d4.w);
    } else {
#pragma unroll
        for (int j = 0; j < 4; ++j)
            if (i0 + j < N) s += pad_cnt(deg[i0 + j]);
    }
    sh[t] = s;
    __syncthreads();
#pragma unroll
    for (int d = 128; d > 0; d >>= 1) {
        if (t < d) sh[t] += sh[t + d];
        __syncthreads();
    }
    if (t == 0) bsum[blockIdx.x] = sh[0];
}

__global__ __launch_bounds__(256) void scan_offsets(
    const int* __restrict__ deg, const int* __restrict__ bsum,
    int* __restrict__ offs, int* __restrict__ cursor, int N, int B)
{
    __shared__ int sh[256];
    __shared__ int sbase;
    const int b = blockIdx.x, t = threadIdx.x;

    int v = (t < b && t < B) ? bsum[t] : 0;   // B <= 256
    sh[t] = v;
    __syncthreads();
#pragma unroll
    for (int d = 128; d > 0; d >>= 1) {
        if (t < d) sh[t] += sh[t + d];
        __syncthreads();
    }
    if (t == 0) sbase = sh[0];
    __syncthreads();

    const int i0 = b * 1024 + t * 4;
    int c[4], s = 0;
#pragma unroll
    for (int j = 0; j < 4; ++j) {
        int i = i0 + j;
        c[j] = (i < N) ? pad_cnt(deg[i]) : 0;
        s += c[j];
    }
    sh[t] = s;
    __syncthreads();
    for (int d = 1; d < 256; d <<= 1) {
        int o = (t >= d) ? sh[t - d] : 0;
        __syncthreads();
        sh[t] += o;
        __syncthreads();
    }
    int run = sbase + sh[t] - s;   // exclusive prefix
#pragma unroll
    for (int j = 0; j < 4; ++j) {
        int i = i0 + j;
        if (i < N) {
            offs[i]   = run;
            cursor[i] = run;
            run += c[j];
        }
    }
    if (b == B - 1 && t == 255) offs[N] = run;
}

__global__ void compute_dinv(const int* __restrict__ deg, float* __restrict__ dinv, int N)
{
    int i = blockIdx.x * 256 + threadIdx.x;
    if (i < N) dinv[i] = rsqrtf((float)(deg[i] + 1));  // +1 self loop
}

__global__ void scatter_csr(const int* __restrict__ src, const int* __restrict__ dst,
                            int E, const float* __restrict__ dinv,
                            int* __restrict__ cursor,
                            int* __restrict__ csr_src, float* __restrict__ csr_val)
{
    int e = blockIdx.x * 256 + threadIdx.x;
    if (e < E) {
        int s = src[e], d = dst[e];
        int pos = atomicAdd(&cursor[d], 1);
        csr_src[pos] = s;
        csr_val[pos] = dinv[s] * dinv[d];
    }
}

__global__ void fill_self_pad(const int* __restrict__ offs, const int* __restrict__ deg,
                              const float* __restrict__ dinv,
                              int* __restrict__ csr_src, float* __restrict__ csr_val, int N)
{
    int i = blockIdx.x * 256 + threadIdx.x;
    if (i < N) {
        int base = offs[i], d = deg[i], end = offs[i + 1];
        float di = dinv[i];
        csr_src[base + d] = i;
        csr_val[base + d] = di * di;
        for (int p = base + d + 1; p < end; ++p) {
            csr_src[p] = i;
            csr_val[p] = 0.f;
        }
    }
}

// ---------------------------------------------------------------------------
// One APPNP step (fp16 features): nxt = (1-a)*(A_hat @ cur) + a*h0.
// One wave per node; four 16-lane groups, 8 feats (16B) per lane; 2-stage
// software pipeline (R8 form — depth-3 measured neutral). fp32 accumulation,
// butterfly __shfl_xor(16/32) combine. Final step writes fp32 to fout.
// ---------------------------------------------------------------------------
__global__ __launch_bounds__(256) void appnp_step(
    const _Float16* __restrict__ cur, const _Float16* __restrict__ h0,
    const int* __restrict__ offs,
    const int* __restrict__ csr_src, const float* __restrict__ csr_val,
    _Float16* __restrict__ nxt, float* __restrict__ fout, int N)
{
    int wv = (int)((blockIdx.x * 256u + threadIdx.x) >> 6);
    if (wv >= N) return;
    const int i    = __builtin_amdgcn_readfirstlane(wv);
    const int lane = (int)(threadIdx.x & 63u);
    const int g    = lane >> 4;          // group 0..3
    const int fl   = (lane & 15) * 8;    // feature offset

    int e   = offs[i];
    int end = offs[i + 1];

    f32x4 accL = (f32x4){0.f, 0.f, 0.f, 0.f};
    f32x4 accH = (f32x4){0.f, 0.f, 0.f, 0.f};

    // stage first 8 edges (groups: edges e+g and e+4+g)
    int   iA = csr_src[e + g],     iB = csr_src[e + 4 + g];
    float wA = csr_val[e + g],     wB = csr_val[e + 4 + g];
    h16x8 vA = *(const h16x8*)(cur + (size_t)iA * 128 + fl);
    h16x8 vB = *(const h16x8*)(cur + (size_t)iB * 128 + fl);

    for (e += 8; e < end; e += 8) {
        int   iA2 = csr_src[e + g],     iB2 = csr_src[e + 4 + g];
        float wA2 = csr_val[e + g],     wB2 = csr_val[e + 4 + g];
        h16x8 vA2 = *(const h16x8*)(cur + (size_t)iA2 * 128 + fl);
        h16x8 vB2 = *(const h16x8*)(cur + (size_t)iB2 * 128 + fl);
#pragma unroll
        for (int j = 0; j < 4; ++j) {
            accL[j] = fmaf(wA, (float)vA[j],     accL[j]);
            accH[j] = fmaf(wA, (float)vA[4 + j], accH[j]);
            accL[j] = fmaf(wB, (float)vB[j],     accL[j]);
            accH[j] = fmaf(wB, (float)vB[4 + j], accH[j]);
        }
        wA = wA2; wB = wB2; vA = vA2; vB = vB2;
    }
#pragma unroll
    for (int j = 0; j < 4; ++j) {
        accL[j] = fmaf(wA, (float)vA[j],     accL[j]);
        accH[j] = fmaf(wA, (float)vA[4 + j], accH[j]);
        accL[j] = fmaf(wB, (float)vB[j],     accL[j]);
        accH[j] = fmaf(wB, (float)vB[4 + j], accH[j]);
    }

    // combine the four group partial sums (butterfly)
#pragma unroll
    for (int j = 0; j < 4; ++j) {
        accL[j] += __shfl_xor(accL[j], 16);
        accL[j] += __shfl_xor(accL[j], 32);
        accH[j] += __shfl_xor(accH[j], 16);
        accH[j] += __shfl_xor(accH[j], 32);
    }

    if (lane < 16) {
        h16x8 hv = *(const h16x8*)(h0 + (size_t)i * 128 + fl);
        float o[8];
#pragma unroll
        for (int j = 0; j < 4; ++j) {
            o[j]     = ALPHA_F * (float)hv[j]     + (1.f - ALPHA_F) * accL[j];
            o[4 + j] = ALPHA_F * (float)hv[4 + j] + (1.f - ALPHA_F) * accH[j];
        }
        if (fout) {
            f32x4 o0, o1;
#pragma unroll
            for (int j = 0; j < 4; ++j) { o0[j] = o[j]; o1[j] = o[4 + j]; }
            *(f32x4*)(fout + (size_t)i * 128 + fl)     = o0;
            *(f32x4*)(fout + (size_t)i * 128 + fl + 4) = o1;
        } else {
            h16x8 o16;
#pragma unroll
            for (int j = 0; j < 8; ++j) o16[j] = (_Float16)o[j];
            *(h16x8*)(nxt + (size_t)i * 128 + fl) = o16;
        }
    }
}

// ---------------------------------------------------------------------------
static inline size_t align_up(size_t x) { return (x + 255) & ~(size_t)255; }

extern "C" void kernel_launch(void* const* d_in, const int* in_sizes, int n_in,
                              void* d_out, int out_size, void* d_ws, size_t ws_size,
                              hipStream_t stream)
{
    const float* x   = (const float*)d_in[0];
    const int*   ei  = (const int*)d_in[1];
    const float* W1  = (const float*)d_in[2];
    const float* b1  = (const float*)d_in[3];
    const float* g1  = (const float*)d_in[4];
    const float* be1 = (const float*)d_in[5];
    const float* m1  = (const float*)d_in[6];
    const float* v1  = (const float*)d_in[7];
    const float* W2  = (const float*)d_in[8];
    const float* b2  = (const float*)d_in[9];
    const float* g2  = (const float*)d_in[10];
    const float* be2 = (const float*)d_in[11];
    const float* m2  = (const float*)d_in[12];
    const float* v2  = (const float*)d_in[13];

    const int N = in_sizes[0] / 512;   // 50000
    const int E = in_sizes[1] / 2;     // 800000
    const int* src = ei;
    const int* dst = ei + E;
    const int CSR_CAP = E + 8 * N + 64;
    const int NB = (N + 1023) / 1024;  // 49

    char* ws = (char*)d_ws;
    size_t off = 0;
    _Float16* hAh = (_Float16*)(ws + off); off += align_up((size_t)N * 128 * 2);
    _Float16* h0h = (_Float16*)(ws + off); off += align_up((size_t)N * 128 * 2);
    _Float16* p0  = (_Float16*)(ws + off); off += align_up((size_t)N * 128 * 2);
    _Float16* p1  = (_Float16*)(ws + off); off += align_up((size_t)N * 128 * 2);
    int*    deg  = (int*)(ws + off);    off += align_up((size_t)N * 4);
    float*  dinv = (float*)(ws + off);  off += align_up((size_t)N * 4);
    int*    offs = (int*)(ws + off);    off += align_up((size_t)(N + 1) * 4);
    int*    curs = (int*)(ws + off);    off += align_up((size_t)N * 4);
    int*    bsum = (int*)(ws + off);    off += align_up((size_t)256 * 4);
    int*    csrs = (int*)(ws + off);    off += align_up((size_t)CSR_CAP * 4);
    float*  csrv = (float*)(ws + off);  off += align_up((size_t)CSR_CAP * 4);
    _Float16* w1t = (_Float16*)(ws + off); off += align_up((size_t)512 * 128 * 2);
    _Float16* w2t = (_Float16*)(ws + off); off += align_up((size_t)128 * 128 * 2);

    // --- graph preprocessing ---
    hipMemsetAsync(deg, 0, (size_t)N * 4, stream);
    count_deg<<<(E + 255) / 256, 256, 0, stream>>>(dst, E, deg);
    scan_block_sums<<<NB, 256, 0, stream>>>(deg, bsum, N);
    scan_offsets<<<NB, 256, 0, stream>>>(deg, bsum, offs, curs, N, NB);
    compute_dinv<<<(N + 255) / 256, 256, 0, stream>>>(deg, dinv, N);
    scatter_csr<<<(E + 255) / 256, 256, 0, stream>>>(src, dst, E, dinv, curs, csrs, csrv);
    fill_self_pad<<<(N + 255) / 256, 256, 0, stream>>>(offs, deg, dinv, csrs, csrv, N);

    // --- weights -> transposed fp16 ---
    convert_wt16<<<(512 * 128 + 255) / 256, 256, 0, stream>>>(W1, w1t, 512);
    convert_wt16<<<(128 * 128 + 255) / 256, 256, 0, stream>>>(W2, w2t, 128);

    // --- MLP: hAh = BN1(relu(x@W1+b1)) fp16; h0h = BN2(hAh@W2+b2) fp16 ---
    gemm_ksplit_bn<false, true><<<(N + 15) / 16, 256, 0, stream>>>(
        x, w1t, b1, g1, be1, m1, v1, hAh, N, 512, 1);
    gemm_ksplit_bn<true, true><<<(N + 15) / 16, 256, 0, stream>>>(
        hAh, w2t, b2, g2, be2, m2, v2, h0h, N, 128, 0);

    // --- 10 propagation steps (fp16 ping-pong); step 10 writes fp32 d_out ---
    const _Float16* cur = h0h;
    for (int k = 0; k < 10; ++k) {
        _Float16* nxt = (k & 1) ? p1 : p0;
        float* fo = (k == 9) ? (float*)d_out : nullptr;
        appnp_step<<<(N + 3) / 4, 256, 0, stream>>>(
            cur, h0h, offs, csrs, csrv, nxt, fo, N);
        cur = nxt;
    }

    (void)n_in; (void)out_size; (void)ws_size;
}

// Round 11
// 454.360 us; speedup vs baseline: 1.1657x; 1.1025x over previous
//
#include <hip/hip_runtime.h>

#define ALPHA_F 0.1f
#define EPS_F   1e-5f

typedef float    f32x4 __attribute__((ext_vector_type(4)));
typedef _Float16 h16x8 __attribute__((ext_vector_type(8)));

__device__ __forceinline__ void gll16(const void* g, void* l)
{
    __builtin_amdgcn_global_load_lds(
        (const __attribute__((address_space(1))) void*)g,
        (__attribute__((address_space(3))) void*)l, 16, 0, 0);
}

// padded count per node: self-loop + edges, rounded up to multiple of 8
__device__ __forceinline__ int pad_cnt(int d) { return (d + 8) & ~7; }

// ---------------------------------------------------------------------------
// W [K x 128] fp32 -> staging-interleaved fp16 layout:
// k-step i (32 k), k-group kg (8 k), col n:
//   Wstg[i*4096 + (kg*128 + n)*8 + j] = W[(i*32 + kg*8 + j)*128 + n]
// so each k-step is one contiguous 8 KB block (perfect global_load_lds
// coalescing) and LDS reads ([kg][n] 16B units) are conflict-free.
// ---------------------------------------------------------------------------
__global__ void convert_wstg(const float* __restrict__ W,
                             _Float16* __restrict__ Wstg, int K)
{
    int idx = blockIdx.x * 256 + threadIdx.x;
    if (idx < K * 128) {
        int k = idx >> 7, n = idx & 127;
        int i = k >> 5, kg = (k >> 3) & 3, j = k & 7;
        Wstg[(size_t)i * 4096 + (kg * 128 + n) * 8 + j] = (_Float16)W[idx];
    }
}

// ---------------------------------------------------------------------------
// out[M,128] = BN( act(A[M,K] @ W + bias) ), fp16 MFMA, fp32 accumulate.
// m97-style: 64x128 tile, BK=32, 4 waves; A and W staged via
// global_load_lds into double-buffered LDS; ONE barrier per k-step.
// A row-major in LDS with XOR-on-source chunk swizzle (involution, applied
// again on the ds_read side) -> coalesced global reads AND <=2-way banks.
// ---------------------------------------------------------------------------
template<bool A_HALF, bool OUT_HALF>
__global__ __launch_bounds__(256) void gemm_stage_bn(
    const void* __restrict__ Av,
    const _Float16* __restrict__ Wstg,
    const float* __restrict__ bias,
    const float* __restrict__ gamma, const float* __restrict__ beta,
    const float* __restrict__ mean,  const float* __restrict__ var,
    void* __restrict__ outv, int M, int K, int do_relu)
{
    __shared__ __align__(16) char Abuf[2][8192];
    __shared__ __align__(16) char Wbuf[2][8192];

    const int t   = threadIdx.x;       // 0..255
    const int w   = t >> 6;            // wave 0..3
    const int l   = t & 63;
    const int l15 = l & 15;
    const int lk  = l >> 4;            // 0..3
    const int bm  = blockIdx.x * 64;
    const int nk  = K >> 5;
    const int row = w * 16 + l15;      // this lane's tile row (0..63)

    f32x4 acc[8];
#pragma unroll
    for (int f = 0; f < 8; ++f) acc[f] = (f32x4){0.f, 0.f, 0.f, 0.f};

    auto stage = [&](int buf, int i) {
        // W tile: contiguous 8 KB block, 512 slots of 16B; 2 calls/thread
        const char* wsrc = (const char*)Wstg + (size_t)i * 8192;
#pragma unroll
        for (int c = 0; c < 2; ++c) {
            const int base = w * 128 + c * 64;   // wave-uniform slot base
            gll16(wsrc + (size_t)(base + l) * 16, &Wbuf[buf][base * 16]);
        }
        // A tile: 64 rows x 32 k
        if (A_HALF) {
            // fp16: 4 KB = 256 slots; 1 call/thread. row=sl>>2, ch=(sl&3)^(row&3)
            const int base = w * 64;
            const int sl   = base + l;
            const int r    = sl >> 2;
            const int ch   = (sl & 3) ^ (r & 3);
            int gr = bm + r; gr = (gr < M) ? gr : (M - 1);
            const char* src = (const char*)Av + ((size_t)gr * K + i * 32) * 2
                              + (size_t)ch * 16;
            gll16(src, &Abuf[buf][base * 16]);
        } else {
            // fp32: 8 KB = 512 slots; 2 calls/thread. row=sl>>3, ch=(sl&7)^(row&7)
#pragma unroll
            for (int c = 0; c < 2; ++c) {
                const int base = w * 128 + c * 64;
                const int sl   = base + l;
                const int r    = sl >> 3;
                const int ch   = (sl & 7) ^ (r & 7);
                int gr = bm + r; gr = (gr < M) ? gr : (M - 1);
                const char* src = (const char*)Av + ((size_t)gr * K + i * 32) * 4
                                  + (size_t)ch * 16;
                gll16(src, &Abuf[buf][base * 16]);
            }
        }
    };

    auto compute = [&](int buf) {
        h16x8 a;
        if (A_HALF) {
            a = *(const h16x8*)&Abuf[buf][(row * 4 + (lk ^ (row & 3))) * 16];
        } else {
            f32x4 a0 = *(const f32x4*)&Abuf[buf][(row * 8 + ((2 * lk)     ^ (row & 7))) * 16];
            f32x4 a1 = *(const f32x4*)&Abuf[buf][(row * 8 + ((2 * lk + 1) ^ (row & 7))) * 16];
#pragma unroll
            for (int j = 0; j < 4; ++j) {
                a[j]     = (_Float16)a0[j];
                a[4 + j] = (_Float16)a1[j];
            }
        }
#pragma unroll
        for (int f = 0; f < 8; ++f) {
            h16x8 b = *(const h16x8*)&Wbuf[buf][(lk * 128 + f * 16 + l15) * 16];
            acc[f] = __builtin_amdgcn_mfma_f32_16x16x32_f16(a, b, acc[f], 0, 0, 0);
        }
    };

    stage(0, 0);
    for (int i = 0; i < nk; ++i) {
        __syncthreads();                  // buf i staged (vmcnt drain at barrier)
        if (i + 1 < nk) stage((i + 1) & 1, i + 1);
        compute(i & 1);
    }

    // epilogue: bias -> (relu) -> BN.  D: col=l15, row=lk*4+rr
#pragma unroll
    for (int f = 0; f < 8; ++f) {
        const int col = f * 16 + l15;
        float s  = gamma[col] * rsqrtf(var[col] + EPS_F);
        float sh = beta[col] - mean[col] * s;
        float bb = bias[col];
#pragma unroll
        for (int rr = 0; rr < 4; ++rr) {
            int rg = bm + w * 16 + lk * 4 + rr;
            if (rg < M) {
                float v = acc[f][rr] + bb;
                if (do_relu) v = fmaxf(v, 0.f);
                v = v * s + sh;
                if (OUT_HALF) ((_Float16*)outv)[(size_t)rg * 128 + col] = (_Float16)v;
                else          ((float*)outv)[(size_t)rg * 128 + col]    = v;
            }
        }
    }
}

// ---------------------------------------------------------------------------
// Graph preprocessing (per launch)
// ---------------------------------------------------------------------------
__global__ void count_deg(const int* __restrict__ dst, int E, int* __restrict__ deg)
{
    int e = blockIdx.x * 256 + threadIdx.x;
    if (e < E) atomicAdd(&deg[dst[e]], 1);
}

__global__ __launch_bounds__(256) void scan_block_sums(
    const int* __restrict__ deg, int* __restrict__ bsum, int N)
{
    __shared__ int sh[256];
    const int t  = threadIdx.x;
    const int i0 = blockIdx.x * 1024 + t * 4;
    int s = 0;
    if (i0 + 3 < N) {
        int4 d4 = *(const int4*)(deg + i0);
        s = pad_cnt(d4.x) + pad_cnt(d4.y) + pad_cnt(d4.z) + pad_cnt(d4.w);
    } else {
#pragma unroll
        for (int j = 0; j < 4; ++j)
            if (i0 + j < N) s += pad_cnt(deg[i0 + j]);
    }
    sh[t] = s;
    __syncthreads();
#pragma unroll
    for (int d = 128; d > 0; d >>= 1) {
        if (t < d) sh[t] += sh[t + d];
        __syncthreads();
    }
    if (t == 0) bsum[blockIdx.x] = sh[0];
}

__global__ __launch_bounds__(256) void scan_offsets(
    const int* __restrict__ deg, const int* __restrict__ bsum,
    int* __restrict__ offs, int* __restrict__ cursor, int N, int B)
{
    __shared__ int sh[256];
    __shared__ int sbase;
    const int b = blockIdx.x, t = threadIdx.x;

    int v = (t < b && t < B) ? bsum[t] : 0;   // B <= 256
    sh[t] = v;
    __syncthreads();
#pragma unroll
    for (int d = 128; d > 0; d >>= 1) {
        if (t < d) sh[t] += sh[t + d];
        __syncthreads();
    }
    if (t == 0) sbase = sh[0];
    __syncthreads();

    const int i0 = b * 1024 + t * 4;
    int c[4], s = 0;
#pragma unroll
    for (int j = 0; j < 4; ++j) {
        int i = i0 + j;
        c[j] = (i < N) ? pad_cnt(deg[i]) : 0;
        s += c[j];
    }
    sh[t] = s;
    __syncthreads();
    for (int d = 1; d < 256; d <<= 1) {
        int o = (t >= d) ? sh[t - d] : 0;
        __syncthreads();
        sh[t] += o;
        __syncthreads();
    }
    int run = sbase + sh[t] - s;   // exclusive prefix
#pragma unroll
    for (int j = 0; j < 4; ++j) {
        int i = i0 + j;
        if (i < N) {
            offs[i]   = run;
            cursor[i] = run;
            run += c[j];
        }
    }
    if (b == B - 1 && t == 255) offs[N] = run;
}

__global__ void compute_dinv(const int* __restrict__ deg, float* __restrict__ dinv, int N)
{
    int i = blockIdx.x * 256 + threadIdx.x;
    if (i < N) dinv[i] = rsqrtf((float)(deg[i] + 1));  // +1 self loop
}

__global__ void scatter_csr(const int* __restrict__ src, const int* __restrict__ dst,
                            int E, const float* __restrict__ dinv,
                            int* __restrict__ cursor,
                            int* __restrict__ csr_src, float* __restrict__ csr_val)
{
    int e = blockIdx.x * 256 + threadIdx.x;
    if (e < E) {
        int s = src[e], d = dst[e];
        int pos = atomicAdd(&cursor[d], 1);
        csr_src[pos] = s;
        csr_val[pos] = dinv[s] * dinv[d];
    }
}

__global__ void fill_self_pad(const int* __restrict__ offs, const int* __restrict__ deg,
                              const float* __restrict__ dinv,
                              int* __restrict__ csr_src, float* __restrict__ csr_val, int N)
{
    int i = blockIdx.x * 256 + threadIdx.x;
    if (i < N) {
        int base = offs[i], d = deg[i], end = offs[i + 1];
        float di = dinv[i];
        csr_src[base + d] = i;
        csr_val[base + d] = di * di;
        for (int p = base + d + 1; p < end; ++p) {
            csr_src[p] = i;
            csr_val[p] = 0.f;
        }
    }
}

// ---------------------------------------------------------------------------
// One APPNP step (fp16 features): nxt = (1-a)*(A_hat @ cur) + a*h0.
// One wave per node; four 16-lane groups, 8 feats (16B) per lane; 2-stage
// software pipeline. fp32 accumulation, butterfly __shfl_xor(16/32) combine.
// Final step writes fp32 to fout.
// ---------------------------------------------------------------------------
__global__ __launch_bounds__(256) void appnp_step(
    const _Float16* __restrict__ cur, const _Float16* __restrict__ h0,
    const int* __restrict__ offs,
    const int* __restrict__ csr_src, const float* __restrict__ csr_val,
    _Float16* __restrict__ nxt, float* __restrict__ fout, int N)
{
    int wv = (int)((blockIdx.x * 256u + threadIdx.x) >> 6);
    if (wv >= N) return;
    const int i    = __builtin_amdgcn_readfirstlane(wv);
    const int lane = (int)(threadIdx.x & 63u);
    const int g    = lane >> 4;          // group 0..3
    const int fl   = (lane & 15) * 8;    // feature offset

    int e   = offs[i];
    int end = offs[i + 1];

    f32x4 accL = (f32x4){0.f, 0.f, 0.f, 0.f};
    f32x4 accH = (f32x4){0.f, 0.f, 0.f, 0.f};

    int   iA = csr_src[e + g],     iB = csr_src[e + 4 + g];
    float wA = csr_val[e + g],     wB = csr_val[e + 4 + g];
    h16x8 vA = *(const h16x8*)(cur + (size_t)iA * 128 + fl);
    h16x8 vB = *(const h16x8*)(cur + (size_t)iB * 128 + fl);

    for (e += 8; e < end; e += 8) {
        int   iA2 = csr_src[e + g],     iB2 = csr_src[e + 4 + g];
        float wA2 = csr_val[e + g],     wB2 = csr_val[e + 4 + g];
        h16x8 vA2 = *(const h16x8*)(cur + (size_t)iA2 * 128 + fl);
        h16x8 vB2 = *(const h16x8*)(cur + (size_t)iB2 * 128 + fl);
#pragma unroll
        for (int j = 0; j < 4; ++j) {
            accL[j] = fmaf(wA, (float)vA[j],     accL[j]);
            accH[j] = fmaf(wA, (float)vA[4 + j], accH[j]);
            accL[j] = fmaf(wB, (float)vB[j],     accL[j]);
            accH[j] = fmaf(wB, (float)vB[4 + j], accH[j]);
        }
        wA = wA2; wB = wB2; vA = vA2; vB = vB2;
    }
#pragma unroll
    for (int j = 0; j < 4; ++j) {
        accL[j] = fmaf(wA, (float)vA[j],     accL[j]);
        accH[j] = fmaf(wA, (float)vA[4 + j], accH[j]);
        accL[j] = fmaf(wB, (float)vB[j],     accL[j]);
        accH[j] = fmaf(wB, (float)vB[4 + j], accH[j]);
    }

#pragma unroll
    for (int j = 0; j < 4; ++j) {
        accL[j] += __shfl_xor(accL[j], 16);
        accL[j] += __shfl_xor(accL[j], 32);
        accH[j] += __shfl_xor(accH[j], 16);
        accH[j] += __shfl_xor(accH[j], 32);
    }

    if (lane < 16) {
        h16x8 hv = *(const h16x8*)(h0 + (size_t)i * 128 + fl);
        float o[8];
#pragma unroll
        for (int j = 0; j < 4; ++j) {
            o[j]     = ALPHA_F * (float)hv[j]     + (1.f - ALPHA_F) * accL[j];
            o[4 + j] = ALPHA_F * (float)hv[4 + j] + (1.f - ALPHA_F) * accH[j];
        }
        if (fout) {
            f32x4 o0, o1;
#pragma unroll
            for (int j = 0; j < 4; ++j) { o0[j] = o[j]; o1[j] = o[4 + j]; }
            *(f32x4*)(fout + (size_t)i * 128 + fl)     = o0;
            *(f32x4*)(fout + (size_t)i * 128 + fl + 4) = o1;
        } else {
            h16x8 o16;
#pragma unroll
            for (int j = 0; j < 8; ++j) o16[j] = (_Float16)o[j];
            *(h16x8*)(nxt + (size_t)i * 128 + fl) = o16;
        }
    }
}

// ---------------------------------------------------------------------------
static inline size_t align_up(size_t x) { return (x + 255) & ~(size_t)255; }

extern "C" void kernel_launch(void* const* d_in, const int* in_sizes, int n_in,
                              void* d_out, int out_size, void* d_ws, size_t ws_size,
                              hipStream_t stream)
{
    const float* x   = (const float*)d_in[0];
    const int*   ei  = (const int*)d_in[1];
    const float* W1  = (const float*)d_in[2];
    const float* b1  = (const float*)d_in[3];
    const float* g1  = (const float*)d_in[4];
    const float* be1 = (const float*)d_in[5];
    const float* m1  = (const float*)d_in[6];
    const float* v1  = (const float*)d_in[7];
    const float* W2  = (const float*)d_in[8];
    const float* b2  = (const float*)d_in[9];
    const float* g2  = (const float*)d_in[10];
    const float* be2 = (const float*)d_in[11];
    const float* m2  = (const float*)d_in[12];
    const float* v2  = (const float*)d_in[13];

    const int N = in_sizes[0] / 512;   // 50000
    const int E = in_sizes[1] / 2;     // 800000
    const int* src = ei;
    const int* dst = ei + E;
    const int CSR_CAP = E + 8 * N + 64;
    const int NB = (N + 1023) / 1024;  // 49

    char* ws = (char*)d_ws;
    size_t off = 0;
    _Float16* hAh = (_Float16*)(ws + off); off += align_up((size_t)N * 128 * 2);
    _Float16* h0h = (_Float16*)(ws + off); off += align_up((size_t)N * 128 * 2);
    _Float16* p0  = (_Float16*)(ws + off); off += align_up((size_t)N * 128 * 2);
    _Float16* p1  = (_Float16*)(ws + off); off += align_up((size_t)N * 128 * 2);
    int*    deg  = (int*)(ws + off);    off += align_up((size_t)N * 4);
    float*  dinv = (float*)(ws + off);  off += align_up((size_t)N * 4);
    int*    offs = (int*)(ws + off);    off += align_up((size_t)(N + 1) * 4);
    int*    curs = (int*)(ws + off);    off += align_up((size_t)N * 4);
    int*    bsum = (int*)(ws + off);    off += align_up((size_t)256 * 4);
    int*    csrs = (int*)(ws + off);    off += align_up((size_t)CSR_CAP * 4);
    float*  csrv = (float*)(ws + off);  off += align_up((size_t)CSR_CAP * 4);
    _Float16* w1s = (_Float16*)(ws + off); off += align_up((size_t)512 * 128 * 2);
    _Float16* w2s = (_Float16*)(ws + off); off += align_up((size_t)128 * 128 * 2);

    // --- graph preprocessing ---
    hipMemsetAsync(deg, 0, (size_t)N * 4, stream);
    count_deg<<<(E + 255) / 256, 256, 0, stream>>>(dst, E, deg);
    scan_block_sums<<<NB, 256, 0, stream>>>(deg, bsum, N);
    scan_offsets<<<NB, 256, 0, stream>>>(deg, bsum, offs, curs, N, NB);
    compute_dinv<<<(N + 255) / 256, 256, 0, stream>>>(deg, dinv, N);
    scatter_csr<<<(E + 255) / 256, 256, 0, stream>>>(src, dst, E, dinv, curs, csrs, csrv);
    fill_self_pad<<<(N + 255) / 256, 256, 0, stream>>>(offs, deg, dinv, csrs, csrv, N);

    // --- weights -> staging-interleaved fp16 ---
    convert_wstg<<<(512 * 128 + 255) / 256, 256, 0, stream>>>(W1, w1s, 512);
    convert_wstg<<<(128 * 128 + 255) / 256, 256, 0, stream>>>(W2, w2s, 128);

    // --- MLP: hAh = BN1(relu(x@W1+b1)) fp16; h0h = BN2(hAh@W2+b2) fp16 ---
    gemm_stage_bn<false, true><<<(N + 63) / 64, 256, 0, stream>>>(
        x, w1s, b1, g1, be1, m1, v1, hAh, N, 512, 1);
    gemm_stage_bn<true, true><<<(N + 63) / 64, 256, 0, stream>>>(
        hAh, w2s, b2, g2, be2, m2, v2, h0h, N, 128, 0);

    // --- 10 propagation steps (fp16 ping-pong); step 10 writes fp32 d_out ---
    const _Float16* cur = h0h;
    for (int k = 0; k < 10; ++k) {
        _Float16* nxt = (k & 1) ? p1 : p0;
        float* fo = (k == 9) ? (float*)d_out : nullptr;
        appnp_step<<<(N + 3) / 4, 256, 0, stream>>>(
            cur, h0h, offs, csrs, csrv, nxt, fo, N);
        cur = nxt;
    }

    (void)n_in; (void)out_size; (void)ws_size;
}

// Round 12
// 438.156 us; speedup vs baseline: 1.2088x; 1.0370x over previous
//
#include <hip/hip_runtime.h>

#define ALPHA_F 0.1f
#define EPS_F   1e-5f

typedef float    f32x4 __attribute__((ext_vector_type(4)));
typedef _Float16 h16x8 __attribute__((ext_vector_type(8)));

__device__ __forceinline__ void gll16(const void* g, void* l)
{
    __builtin_amdgcn_global_load_lds(
        (const __attribute__((address_space(1))) void*)g,
        (__attribute__((address_space(3))) void*)l, 16, 0, 0);
}

// padded count per node: self-loop + edges, rounded up to multiple of 8
__device__ __forceinline__ int pad_cnt(int d) { return (d + 8) & ~7; }

// ---------------------------------------------------------------------------
// W [K x 128] fp32 -> staging-interleaved fp16 layout (one 8 KB block per
// 32-k step; LDS reads conflict-free).
// ---------------------------------------------------------------------------
__global__ void convert_wstg(const float* __restrict__ W,
                             _Float16* __restrict__ Wstg, int K)
{
    int idx = blockIdx.x * 256 + threadIdx.x;
    if (idx < K * 128) {
        int k = idx >> 7, n = idx & 127;
        int i = k >> 5, kg = (k >> 3) & 3, j = k & 7;
        Wstg[(size_t)i * 4096 + (kg * 128 + n) * 8 + j] = (_Float16)W[idx];
    }
}

// ---------------------------------------------------------------------------
// out[M,128] = BN( act(A[M,K] @ W + bias) ), fp16 MFMA, fp32 accumulate.
// m97-style: 64x128 tile, BK=32, 4 waves; global_load_lds double-buffered.
// (unchanged from R11 — measured ~13+4 µs for the two GEMMs)
// ---------------------------------------------------------------------------
template<bool A_HALF, bool OUT_HALF>
__global__ __launch_bounds__(256) void gemm_stage_bn(
    const void* __restrict__ Av,
    const _Float16* __restrict__ Wstg,
    const float* __restrict__ bias,
    const float* __restrict__ gamma, const float* __restrict__ beta,
    const float* __restrict__ mean,  const float* __restrict__ var,
    void* __restrict__ outv, int M, int K, int do_relu)
{
    __shared__ __align__(16) char Abuf[2][8192];
    __shared__ __align__(16) char Wbuf[2][8192];

    const int t   = threadIdx.x;       // 0..255
    const int w   = t >> 6;            // wave 0..3
    const int l   = t & 63;
    const int l15 = l & 15;
    const int lk  = l >> 4;            // 0..3
    const int bm  = blockIdx.x * 64;
    const int nk  = K >> 5;
    const int row = w * 16 + l15;      // this lane's tile row (0..63)

    f32x4 acc[8];
#pragma unroll
    for (int f = 0; f < 8; ++f) acc[f] = (f32x4){0.f, 0.f, 0.f, 0.f};

    auto stage = [&](int buf, int i) {
        const char* wsrc = (const char*)Wstg + (size_t)i * 8192;
#pragma unroll
        for (int c = 0; c < 2; ++c) {
            const int base = w * 128 + c * 64;
            gll16(wsrc + (size_t)(base + l) * 16, &Wbuf[buf][base * 16]);
        }
        if (A_HALF) {
            const int base = w * 64;
            const int sl   = base + l;
            const int r    = sl >> 2;
            const int ch   = (sl & 3) ^ (r & 3);
            int gr = bm + r; gr = (gr < M) ? gr : (M - 1);
            const char* src = (const char*)Av + ((size_t)gr * K + i * 32) * 2
                              + (size_t)ch * 16;
            gll16(src, &Abuf[buf][base * 16]);
        } else {
#pragma unroll
            for (int c = 0; c < 2; ++c) {
                const int base = w * 128 + c * 64;
                const int sl   = base + l;
                const int r    = sl >> 3;
                const int ch   = (sl & 7) ^ (r & 7);
                int gr = bm + r; gr = (gr < M) ? gr : (M - 1);
                const char* src = (const char*)Av + ((size_t)gr * K + i * 32) * 4
                                  + (size_t)ch * 16;
                gll16(src, &Abuf[buf][base * 16]);
            }
        }
    };

    auto compute = [&](int buf) {
        h16x8 a;
        if (A_HALF) {
            a = *(const h16x8*)&Abuf[buf][(row * 4 + (lk ^ (row & 3))) * 16];
        } else {
            f32x4 a0 = *(const f32x4*)&Abuf[buf][(row * 8 + ((2 * lk)     ^ (row & 7))) * 16];
            f32x4 a1 = *(const f32x4*)&Abuf[buf][(row * 8 + ((2 * lk + 1) ^ (row & 7))) * 16];
#pragma unroll
            for (int j = 0; j < 4; ++j) {
                a[j]     = (_Float16)a0[j];
                a[4 + j] = (_Float16)a1[j];
            }
        }
#pragma unroll
        for (int f = 0; f < 8; ++f) {
            h16x8 b = *(const h16x8*)&Wbuf[buf][(lk * 128 + f * 16 + l15) * 16];
            acc[f] = __builtin_amdgcn_mfma_f32_16x16x32_f16(a, b, acc[f], 0, 0, 0);
        }
    };

    stage(0, 0);
    for (int i = 0; i < nk; ++i) {
        __syncthreads();
        if (i + 1 < nk) stage((i + 1) & 1, i + 1);
        compute(i & 1);
    }

#pragma unroll
    for (int f = 0; f < 8; ++f) {
        const int col = f * 16 + l15;
        float s  = gamma[col] * rsqrtf(var[col] + EPS_F);
        float sh = beta[col] - mean[col] * s;
        float bb = bias[col];
#pragma unroll
        for (int rr = 0; rr < 4; ++rr) {
            int rg = bm + w * 16 + lk * 4 + rr;
            if (rg < M) {
                float v = acc[f][rr] + bb;
                if (do_relu) v = fmaxf(v, 0.f);
                v = v * s + sh;
                if (OUT_HALF) ((_Float16*)outv)[(size_t)rg * 128 + col] = (_Float16)v;
                else          ((float*)outv)[(size_t)rg * 128 + col]    = v;
            }
        }
    }
}

// ---------------------------------------------------------------------------
// Graph preprocessing (per launch). CSR entries are PACKED int2 {src, val}.
// ---------------------------------------------------------------------------
__global__ void count_deg(const int* __restrict__ dst, int E, int* __restrict__ deg)
{
    int e = blockIdx.x * 256 + threadIdx.x;
    if (e < E) atomicAdd(&deg[dst[e]], 1);
}

__global__ __launch_bounds__(256) void scan_block_sums(
    const int* __restrict__ deg, int* __restrict__ bsum, int N)
{
    __shared__ int sh[256];
    const int t  = threadIdx.x;
    const int i0 = blockIdx.x * 1024 + t * 4;
    int s = 0;
    if (i0 + 3 < N) {
        int4 d4 = *(const int4*)(deg + i0);
        s = pad_cnt(d4.x) + pad_cnt(d4.y) + pad_cnt(d4.z) + pad_cnt(d4.w);
    } else {
#pragma unroll
        for (int j = 0; j < 4; ++j)
            if (i0 + j < N) s += pad_cnt(deg[i0 + j]);
    }
    sh[t] = s;
    __syncthreads();
#pragma unroll
    for (int d = 128; d > 0; d >>= 1) {
        if (t < d) sh[t] += sh[t + d];
        __syncthreads();
    }
    if (t == 0) bsum[blockIdx.x] = sh[0];
}

// also emits dinv (fused former compute_dinv)
__global__ __launch_bounds__(256) void scan_offsets(
    const int* __restrict__ deg, const int* __restrict__ bsum,
    int* __restrict__ offs, int* __restrict__ cursor,
    float* __restrict__ dinv, int N, int B)
{
    __shared__ int sh[256];
    __shared__ int sbase;
    const int b = blockIdx.x, t = threadIdx.x;

    int v = (t < b && t < B) ? bsum[t] : 0;   // B <= 256
    sh[t] = v;
    __syncthreads();
#pragma unroll
    for (int d = 128; d > 0; d >>= 1) {
        if (t < d) sh[t] += sh[t + d];
        __syncthreads();
    }
    if (t == 0) sbase = sh[0];
    __syncthreads();

    const int i0 = b * 1024 + t * 4;
    int c[4], s = 0;
#pragma unroll
    for (int j = 0; j < 4; ++j) {
        int i = i0 + j;
        c[j] = (i < N) ? pad_cnt(deg[i]) : 0;
        s += c[j];
    }
    sh[t] = s;
    __syncthreads();
    for (int d = 1; d < 256; d <<= 1) {
        int o = (t >= d) ? sh[t - d] : 0;
        __syncthreads();
        sh[t] += o;
        __syncthreads();
    }
    int run = sbase + sh[t] - s;   // exclusive prefix
#pragma unroll
    for (int j = 0; j < 4; ++j) {
        int i = i0 + j;
        if (i < N) {
            offs[i]   = run;
            cursor[i] = run;
            dinv[i]   = rsqrtf((float)(deg[i] + 1));   // +1 self loop
            run += c[j];
        }
    }
    if (b == B - 1 && t == 255) offs[N] = run;
}

__global__ void scatter_csr(const int* __restrict__ src, const int* __restrict__ dst,
                            int E, const float* __restrict__ dinv,
                            int* __restrict__ cursor, int2* __restrict__ csr)
{
    int e = blockIdx.x * 256 + threadIdx.x;
    if (e < E) {
        int s = src[e], d = dst[e];
        int pos = atomicAdd(&cursor[d], 1);
        csr[pos] = make_int2(s, __float_as_int(dinv[s] * dinv[d]));
    }
}

__global__ void fill_self_pad(const int* __restrict__ offs, const int* __restrict__ deg,
                              const float* __restrict__ dinv,
                              int2* __restrict__ csr, int N)
{
    int i = blockIdx.x * 256 + threadIdx.x;
    if (i < N) {
        int base = offs[i], d = deg[i], end = offs[i + 1];
        float di = dinv[i];
        csr[base + d] = make_int2(i, __float_as_int(di * di));
        for (int p = base + d + 1; p < end; ++p)
            csr[p] = make_int2(i, 0);
    }
}

// ---------------------------------------------------------------------------
// One APPNP step (fp16 features): nxt = (1-a)*(A_hat @ cur) + a*h0.
// One wave per node; four 16-lane groups; group g handles edges (e+2g,
// e+2g+1): metadata = ONE int4 load per group per iteration. 8 feats (16B)
// per lane, 2-stage software pipeline, fp32 accumulation, butterfly
// __shfl_xor(16/32) combine. Final step writes fp32 to fout.
// ---------------------------------------------------------------------------
__global__ __launch_bounds__(256) void appnp_step(
    const _Float16* __restrict__ cur, const _Float16* __restrict__ h0,
    const int* __restrict__ offs, const int2* __restrict__ csr,
    _Float16* __restrict__ nxt, float* __restrict__ fout, int N)
{
    int wv = (int)((blockIdx.x * 256u + threadIdx.x) >> 6);
    if (wv >= N) return;
    const int i    = __builtin_amdgcn_readfirstlane(wv);
    const int lane = (int)(threadIdx.x & 63u);
    const int g    = lane >> 4;          // group 0..3
    const int fl   = (lane & 15) * 8;    // feature offset

    int e   = offs[i];
    int end = offs[i + 1];

    f32x4 accL = (f32x4){0.f, 0.f, 0.f, 0.f};
    f32x4 accH = (f32x4){0.f, 0.f, 0.f, 0.f};

    // stage first 8 edges: group g owns edges e+2g, e+2g+1
    int4 m = *(const int4*)(csr + e + 2 * g);
    int   iA = m.x,                     iB = m.z;
    float wA = __int_as_float(m.y),     wB = __int_as_float(m.w);
    h16x8 vA = *(const h16x8*)(cur + (size_t)iA * 128 + fl);
    h16x8 vB = *(const h16x8*)(cur + (size_t)iB * 128 + fl);

    for (e += 8; e < end; e += 8) {
        int4 m2 = *(const int4*)(csr + e + 2 * g);
        int   iA2 = m2.x,                 iB2 = m2.z;
        float wA2 = __int_as_float(m2.y), wB2 = __int_as_float(m2.w);
        h16x8 vA2 = *(const h16x8*)(cur + (size_t)iA2 * 128 + fl);
        h16x8 vB2 = *(const h16x8*)(cur + (size_t)iB2 * 128 + fl);
#pragma unroll
        for (int j = 0; j < 4; ++j) {
            accL[j] = fmaf(wA, (float)vA[j],     accL[j]);
            accH[j] = fmaf(wA, (float)vA[4 + j], accH[j]);
            accL[j] = fmaf(wB, (float)vB[j],     accL[j]);
            accH[j] = fmaf(wB, (float)vB[4 + j], accH[j]);
        }
        wA = wA2; wB = wB2; vA = vA2; vB = vB2;
    }
#pragma unroll
    for (int j = 0; j < 4; ++j) {
        accL[j] = fmaf(wA, (float)vA[j],     accL[j]);
        accH[j] = fmaf(wA, (float)vA[4 + j], accH[j]);
        accL[j] = fmaf(wB, (float)vB[j],     accL[j]);
        accH[j] = fmaf(wB, (float)vB[4 + j], accH[j]);
    }

#pragma unroll
    for (int j = 0; j < 4; ++j) {
        accL[j] += __shfl_xor(accL[j], 16);
        accL[j] += __shfl_xor(accL[j], 32);
        accH[j] += __shfl_xor(accH[j], 16);
        accH[j] += __shfl_xor(accH[j], 32);
    }

    if (lane < 16) {
        h16x8 hv = *(const h16x8*)(h0 + (size_t)i * 128 + fl);
        float o[8];
#pragma unroll
        for (int j = 0; j < 4; ++j) {
            o[j]     = ALPHA_F * (float)hv[j]     + (1.f - ALPHA_F) * accL[j];
            o[4 + j] = ALPHA_F * (float)hv[4 + j] + (1.f - ALPHA_F) * accH[j];
        }
        if (fout) {
            f32x4 o0, o1;
#pragma unroll
            for (int j = 0; j < 4; ++j) { o0[j] = o[j]; o1[j] = o[4 + j]; }
            *(f32x4*)(fout + (size_t)i * 128 + fl)     = o0;
            *(f32x4*)(fout + (size_t)i * 128 + fl + 4) = o1;
        } else {
            h16x8 o16;
#pragma unroll
            for (int j = 0; j < 8; ++j) o16[j] = (_Float16)o[j];
            *(h16x8*)(nxt + (size_t)i * 128 + fl) = o16;
        }
    }
}

// ---------------------------------------------------------------------------
static inline size_t align_up(size_t x) { return (x + 255) & ~(size_t)255; }

extern "C" void kernel_launch(void* const* d_in, const int* in_sizes, int n_in,
                              void* d_out, int out_size, void* d_ws, size_t ws_size,
                              hipStream_t stream)
{
    const float* x   = (const float*)d_in[0];
    const int*   ei  = (const int*)d_in[1];
    const float* W1  = (const float*)d_in[2];
    const float* b1  = (const float*)d_in[3];
    const float* g1  = (const float*)d_in[4];
    const float* be1 = (const float*)d_in[5];
    const float* m1  = (const float*)d_in[6];
    const float* v1  = (const float*)d_in[7];
    const float* W2  = (const float*)d_in[8];
    const float* b2  = (const float*)d_in[9];
    const float* g2  = (const float*)d_in[10];
    const float* be2 = (const float*)d_in[11];
    const float* m2  = (const float*)d_in[12];
    const float* v2  = (const float*)d_in[13];

    const int N = in_sizes[0] / 512;   // 50000
    const int E = in_sizes[1] / 2;     // 800000
    const int* src = ei;
    const int* dst = ei + E;
    const int CSR_CAP = E + 8 * N;     // int2 entries
    const int NB = (N + 1023) / 1024;  // 49

    char* ws = (char*)d_ws;
    size_t off = 0;
    _Float16* hAh = (_Float16*)(ws + off); off += align_up((size_t)N * 128 * 2);
    _Float16* h0h = (_Float16*)(ws + off); off += align_up((size_t)N * 128 * 2);
    _Float16* p0  = (_Float16*)(ws + off); off += align_up((size_t)N * 128 * 2);
    _Float16* p1  = (_Float16*)(ws + off); off += align_up((size_t)N * 128 * 2);
    int*    deg  = (int*)(ws + off);    off += align_up((size_t)N * 4);
    float*  dinv = (float*)(ws + off);  off += align_up((size_t)N * 4);
    int*    offs = (int*)(ws + off);    off += align_up((size_t)(N + 1) * 4);
    int*    curs = (int*)(ws + off);    off += align_up((size_t)N * 4);
    int*    bsum = (int*)(ws + off);    off += align_up((size_t)256 * 4);
    int2*   csr  = (int2*)(ws + off);   off += align_up((size_t)CSR_CAP * 8);
    _Float16* w1s = (_Float16*)(ws + off); off += align_up((size_t)512 * 128 * 2);
    _Float16* w2s = (_Float16*)(ws + off); off += align_up((size_t)128 * 128 * 2);

    // --- graph preprocessing ---
    hipMemsetAsync(deg, 0, (size_t)N * 4, stream);
    count_deg<<<(E + 255) / 256, 256, 0, stream>>>(dst, E, deg);
    scan_block_sums<<<NB, 256, 0, stream>>>(deg, bsum, N);
    scan_offsets<<<NB, 256, 0, stream>>>(deg, bsum, offs, curs, dinv, N, NB);
    scatter_csr<<<(E + 255) / 256, 256, 0, stream>>>(src, dst, E, dinv, curs, csr);
    fill_self_pad<<<(N + 255) / 256, 256, 0, stream>>>(offs, deg, dinv, csr, N);

    // --- weights -> staging-interleaved fp16 ---
    convert_wstg<<<(512 * 128 + 255) / 256, 256, 0, stream>>>(W1, w1s, 512);
    convert_wstg<<<(128 * 128 + 255) / 256, 256, 0, stream>>>(W2, w2s, 128);

    // --- MLP: hAh = BN1(relu(x@W1+b1)) fp16; h0h = BN2(hAh@W2+b2) fp16 ---
    gemm_stage_bn<false, true><<<(N + 63) / 64, 256, 0, stream>>>(
        x, w1s, b1, g1, be1, m1, v1, hAh, N, 512, 1);
    gemm_stage_bn<true, true><<<(N + 63) / 64, 256, 0, stream>>>(
        hAh, w2s, b2, g2, be2, m2, v2, h0h, N, 128, 0);

    // --- 10 propagation steps (fp16 ping-pong); step 10 writes fp32 d_out ---
    const _Float16* cur = h0h;
    for (int k = 0; k < 10; ++k) {
        _Float16* nxt = (k & 1) ? p1 : p0;
        float* fo = (k == 9) ? (float*)d_out : nullptr;
        appnp_step<<<(N + 3) / 4, 256, 0, stream>>>(
            cur, h0h, offs, csr, nxt, fo, N);
        cur = nxt;
    }

    (void)n_in; (void)out_size; (void)ws_size;
}

// Round 13
// 430.008 us; speedup vs baseline: 1.2317x; 1.0189x over previous
//
#include <hip/hip_runtime.h>

#define ALPHA_F 0.1f
#define EPS_F   1e-5f

typedef float    f32x4 __attribute__((ext_vector_type(4)));
typedef _Float16 h16x8 __attribute__((ext_vector_type(8)));
typedef _Float16 h16x2 __attribute__((ext_vector_type(2)));

__device__ __forceinline__ void gll16(const void* g, void* l)
{
    __builtin_amdgcn_global_load_lds(
        (const __attribute__((address_space(1))) void*)g,
        (__attribute__((address_space(3))) void*)l, 16, 0, 0);
}

// padded count per node: self-loop + edges, rounded up to multiple of 8
__device__ __forceinline__ int pad_cnt(int d) { return (d + 8) & ~7; }

// ---------------------------------------------------------------------------
// W [K x 128] fp32 -> staging-interleaved fp16 layout (one 8 KB block per
// 32-k step; LDS reads conflict-free).
// ---------------------------------------------------------------------------
__global__ void convert_wstg(const float* __restrict__ W,
                             _Float16* __restrict__ Wstg, int K)
{
    int idx = blockIdx.x * 256 + threadIdx.x;
    if (idx < K * 128) {
        int k = idx >> 7, n = idx & 127;
        int i = k >> 5, kg = (k >> 3) & 3, j = k & 7;
        Wstg[(size_t)i * 4096 + (kg * 128 + n) * 8 + j] = (_Float16)W[idx];
    }
}

// ---------------------------------------------------------------------------
// out[M,128] = BN( act(A[M,K] @ W + bias) ), fp16 MFMA, fp32 accumulate.
// m97-style: 64x128 tile, BK=32, 4 waves; global_load_lds double-buffered.
// (unchanged — measured ~13+4 µs for the two GEMMs)
// ---------------------------------------------------------------------------
template<bool A_HALF, bool OUT_HALF>
__global__ __launch_bounds__(256) void gemm_stage_bn(
    const void* __restrict__ Av,
    const _Float16* __restrict__ Wstg,
    const float* __restrict__ bias,
    const float* __restrict__ gamma, const float* __restrict__ beta,
    const float* __restrict__ mean,  const float* __restrict__ var,
    void* __restrict__ outv, int M, int K, int do_relu)
{
    __shared__ __align__(16) char Abuf[2][8192];
    __shared__ __align__(16) char Wbuf[2][8192];

    const int t   = threadIdx.x;       // 0..255
    const int w   = t >> 6;            // wave 0..3
    const int l   = t & 63;
    const int l15 = l & 15;
    const int lk  = l >> 4;            // 0..3
    const int bm  = blockIdx.x * 64;
    const int nk  = K >> 5;
    const int row = w * 16 + l15;      // this lane's tile row (0..63)

    f32x4 acc[8];
#pragma unroll
    for (int f = 0; f < 8; ++f) acc[f] = (f32x4){0.f, 0.f, 0.f, 0.f};

    auto stage = [&](int buf, int i) {
        const char* wsrc = (const char*)Wstg + (size_t)i * 8192;
#pragma unroll
        for (int c = 0; c < 2; ++c) {
            const int base = w * 128 + c * 64;
            gll16(wsrc + (size_t)(base + l) * 16, &Wbuf[buf][base * 16]);
        }
        if (A_HALF) {
            const int base = w * 64;
            const int sl   = base + l;
            const int r    = sl >> 2;
            const int ch   = (sl & 3) ^ (r & 3);
            int gr = bm + r; gr = (gr < M) ? gr : (M - 1);
            const char* src = (const char*)Av + ((size_t)gr * K + i * 32) * 2
                              + (size_t)ch * 16;
            gll16(src, &Abuf[buf][base * 16]);
        } else {
#pragma unroll
            for (int c = 0; c < 2; ++c) {
                const int base = w * 128 + c * 64;
                const int sl   = base + l;
                const int r    = sl >> 3;
                const int ch   = (sl & 7) ^ (r & 7);
                int gr = bm + r; gr = (gr < M) ? gr : (M - 1);
                const char* src = (const char*)Av + ((size_t)gr * K + i * 32) * 4
                                  + (size_t)ch * 16;
                gll16(src, &Abuf[buf][base * 16]);
            }
        }
    };

    auto compute = [&](int buf) {
        h16x8 a;
        if (A_HALF) {
            a = *(const h16x8*)&Abuf[buf][(row * 4 + (lk ^ (row & 3))) * 16];
        } else {
            f32x4 a0 = *(const f32x4*)&Abuf[buf][(row * 8 + ((2 * lk)     ^ (row & 7))) * 16];
            f32x4 a1 = *(const f32x4*)&Abuf[buf][(row * 8 + ((2 * lk + 1) ^ (row & 7))) * 16];
#pragma unroll
            for (int j = 0; j < 4; ++j) {
                a[j]     = (_Float16)a0[j];
                a[4 + j] = (_Float16)a1[j];
            }
        }
#pragma unroll
        for (int f = 0; f < 8; ++f) {
            h16x8 b = *(const h16x8*)&Wbuf[buf][(lk * 128 + f * 16 + l15) * 16];
            acc[f] = __builtin_amdgcn_mfma_f32_16x16x32_f16(a, b, acc[f], 0, 0, 0);
        }
    };

    stage(0, 0);
    for (int i = 0; i < nk; ++i) {
        __syncthreads();
        if (i + 1 < nk) stage((i + 1) & 1, i + 1);
        compute(i & 1);
    }

#pragma unroll
    for (int f = 0; f < 8; ++f) {
        const int col = f * 16 + l15;
        float s  = gamma[col] * rsqrtf(var[col] + EPS_F);
        float sh = beta[col] - mean[col] * s;
        float bb = bias[col];
#pragma unroll
        for (int rr = 0; rr < 4; ++rr) {
            int rg = bm + w * 16 + lk * 4 + rr;
            if (rg < M) {
                float v = acc[f][rr] + bb;
                if (do_relu) v = fmaxf(v, 0.f);
                v = v * s + sh;
                if (OUT_HALF) ((_Float16*)outv)[(size_t)rg * 128 + col] = (_Float16)v;
                else          ((float*)outv)[(size_t)rg * 128 + col]    = v;
            }
        }
    }
}

// ---------------------------------------------------------------------------
// Graph preprocessing (per launch). CSR entries are PACKED int2 {src, val}.
// ---------------------------------------------------------------------------
__global__ void count_deg(const int* __restrict__ dst, int E, int* __restrict__ deg)
{
    int e = blockIdx.x * 256 + threadIdx.x;
    if (e < E) atomicAdd(&deg[dst[e]], 1);
}

__global__ __launch_bounds__(256) void scan_block_sums(
    const int* __restrict__ deg, int* __restrict__ bsum, int N)
{
    __shared__ int sh[256];
    const int t  = threadIdx.x;
    const int i0 = blockIdx.x * 1024 + t * 4;
    int s = 0;
    if (i0 + 3 < N) {
        int4 d4 = *(const int4*)(deg + i0);
        s = pad_cnt(d4.x) + pad_cnt(d4.y) + pad_cnt(d4.z) + pad_cnt(d4.w);
    } else {
#pragma unroll
        for (int j = 0; j < 4; ++j)
            if (i0 + j < N) s += pad_cnt(deg[i0 + j]);
    }
    sh[t] = s;
    __syncthreads();
#pragma unroll
    for (int d = 128; d > 0; d >>= 1) {
        if (t < d) sh[t] += sh[t + d];
        __syncthreads();
    }
    if (t == 0) bsum[blockIdx.x] = sh[0];
}

// also emits dinv (fused former compute_dinv)
__global__ __launch_bounds__(256) void scan_offsets(
    const int* __restrict__ deg, const int* __restrict__ bsum,
    int* __restrict__ offs, int* __restrict__ cursor,
    float* __restrict__ dinv, int N, int B)
{
    __shared__ int sh[256];
    __shared__ int sbase;
    const int b = blockIdx.x, t = threadIdx.x;

    int v = (t < b && t < B) ? bsum[t] : 0;   // B <= 256
    sh[t] = v;
    __syncthreads();
#pragma unroll
    for (int d = 128; d > 0; d >>= 1) {
        if (t < d) sh[t] += sh[t + d];
        __syncthreads();
    }
    if (t == 0) sbase = sh[0];
    __syncthreads();

    const int i0 = b * 1024 + t * 4;
    int c[4], s = 0;
#pragma unroll
    for (int j = 0; j < 4; ++j) {
        int i = i0 + j;
        c[j] = (i < N) ? pad_cnt(deg[i]) : 0;
        s += c[j];
    }
    sh[t] = s;
    __syncthreads();
    for (int d = 1; d < 256; d <<= 1) {
        int o = (t >= d) ? sh[t - d] : 0;
        __syncthreads();
        sh[t] += o;
        __syncthreads();
    }
    int run = sbase + sh[t] - s;   // exclusive prefix
#pragma unroll
    for (int j = 0; j < 4; ++j) {
        int i = i0 + j;
        if (i < N) {
            offs[i]   = run;
            cursor[i] = run;
            dinv[i]   = rsqrtf((float)(deg[i] + 1));   // +1 self loop
            run += c[j];
        }
    }
    if (b == B - 1 && t == 255) offs[N] = run;
}

__global__ void scatter_csr(const int* __restrict__ src, const int* __restrict__ dst,
                            int E, const float* __restrict__ dinv,
                            int* __restrict__ cursor, int2* __restrict__ csr)
{
    int e = blockIdx.x * 256 + threadIdx.x;
    if (e < E) {
        int s = src[e], d = dst[e];
        int pos = atomicAdd(&cursor[d], 1);
        csr[pos] = make_int2(s, __float_as_int(dinv[s] * dinv[d]));
    }
}

__global__ void fill_self_pad(const int* __restrict__ offs, const int* __restrict__ deg,
                              const float* __restrict__ dinv,
                              int2* __restrict__ csr, int N)
{
    int i = blockIdx.x * 256 + threadIdx.x;
    if (i < N) {
        int base = offs[i], d = deg[i], end = offs[i + 1];
        float di = dinv[i];
        csr[base + d] = make_int2(i, __float_as_int(di * di));
        for (int p = base + d + 1; p < end; ++p)
            csr[p] = make_int2(i, 0);
    }
}

// ---------------------------------------------------------------------------
// One APPNP step (fp16 features): nxt = (1-a)*(A_hat @ cur) + a*h0.
// PERSISTENT waves: grid = 2048 blocks = 8192 waves (32/CU), each wave
// strides over ~6 nodes — one latency ramp, queues stay full.
// Four 16-lane groups per wave; group g owns edges (e+2g, e+2g+1);
// metadata = one int4/group/iter. FMA in PACKED fp16 (v_pk_fma_f16,
// 4 ops/edge/lane instead of 16); butterfly reduce + alpha-blend in fp32.
// ---------------------------------------------------------------------------
#define NWAVES 8192

__global__ __launch_bounds__(256) void appnp_step(
    const _Float16* __restrict__ cur, const _Float16* __restrict__ h0,
    const int* __restrict__ offs, const int2* __restrict__ csr,
    _Float16* __restrict__ nxt, float* __restrict__ fout, int N)
{
    const int wv0  = __builtin_amdgcn_readfirstlane(
                        (int)((blockIdx.x * 256u + threadIdx.x) >> 6));
    const int lane = (int)(threadIdx.x & 63u);
    const int g    = lane >> 4;          // group 0..3
    const int fl   = (lane & 15) * 8;    // feature offset

    for (int i = wv0; i < N; i += NWAVES) {
        int e   = offs[i];
        int end = offs[i + 1];

        h16x2 acc[4];
#pragma unroll
        for (int j = 0; j < 4; ++j) acc[j] = (h16x2){(_Float16)0, (_Float16)0};

        // stage first 8 edges: group g owns edges e+2g, e+2g+1
        int4 m = *(const int4*)(csr + e + 2 * g);
        h16x8 vA = *(const h16x8*)(cur + (size_t)m.x * 128 + fl);
        h16x8 vB = *(const h16x8*)(cur + (size_t)m.z * 128 + fl);

        for (e += 8; e < end; e += 8) {
            int4 m2 = *(const int4*)(csr + e + 2 * g);
            h16x8 vA2 = *(const h16x8*)(cur + (size_t)m2.x * 128 + fl);
            h16x8 vB2 = *(const h16x8*)(cur + (size_t)m2.z * 128 + fl);
            _Float16 ha = (_Float16)__int_as_float(m.y);
            _Float16 hb = (_Float16)__int_as_float(m.w);
            h16x2 wa = (h16x2){ha, ha}, wb = (h16x2){hb, hb};
#pragma unroll
            for (int j = 0; j < 4; ++j) {
                h16x2 va = (h16x2){vA[2 * j], vA[2 * j + 1]};
                h16x2 vb = (h16x2){vB[2 * j], vB[2 * j + 1]};
                acc[j] = __builtin_elementwise_fma(wa, va, acc[j]);
                acc[j] = __builtin_elementwise_fma(wb, vb, acc[j]);
            }
            m = m2; vA = vA2; vB = vB2;
        }
        {   // tail window
            _Float16 ha = (_Float16)__int_as_float(m.y);
            _Float16 hb = (_Float16)__int_as_float(m.w);
            h16x2 wa = (h16x2){ha, ha}, wb = (h16x2){hb, hb};
#pragma unroll
            for (int j = 0; j < 4; ++j) {
                h16x2 va = (h16x2){vA[2 * j], vA[2 * j + 1]};
                h16x2 vb = (h16x2){vB[2 * j], vB[2 * j + 1]};
                acc[j] = __builtin_elementwise_fma(wa, va, acc[j]);
                acc[j] = __builtin_elementwise_fma(wb, vb, acc[j]);
            }
        }

        // unpack to fp32 and butterfly-combine the four group partials
        float o[8];
#pragma unroll
        for (int j = 0; j < 4; ++j) {
            o[2 * j]     = (float)acc[j][0];
            o[2 * j + 1] = (float)acc[j][1];
        }
#pragma unroll
        for (int j = 0; j < 8; ++j) {
            o[j] += __shfl_xor(o[j], 16);
            o[j] += __shfl_xor(o[j], 32);
        }

        if (lane < 16) {
            h16x8 hv = *(const h16x8*)(h0 + (size_t)i * 128 + fl);
#pragma unroll
            for (int j = 0; j < 8; ++j)
                o[j] = ALPHA_F * (float)hv[j] + (1.f - ALPHA_F) * o[j];
            if (fout) {
                f32x4 o0, o1;
#pragma unroll
                for (int j = 0; j < 4; ++j) { o0[j] = o[j]; o1[j] = o[4 + j]; }
                *(f32x4*)(fout + (size_t)i * 128 + fl)     = o0;
                *(f32x4*)(fout + (size_t)i * 128 + fl + 4) = o1;
            } else {
                h16x8 o16;
#pragma unroll
                for (int j = 0; j < 8; ++j) o16[j] = (_Float16)o[j];
                *(h16x8*)(nxt + (size_t)i * 128 + fl) = o16;
            }
        }
    }
}

// ---------------------------------------------------------------------------
static inline size_t align_up(size_t x) { return (x + 255) & ~(size_t)255; }

extern "C" void kernel_launch(void* const* d_in, const int* in_sizes, int n_in,
                              void* d_out, int out_size, void* d_ws, size_t ws_size,
                              hipStream_t stream)
{
    const float* x   = (const float*)d_in[0];
    const int*   ei  = (const int*)d_in[1];
    const float* W1  = (const float*)d_in[2];
    const float* b1  = (const float*)d_in[3];
    const float* g1  = (const float*)d_in[4];
    const float* be1 = (const float*)d_in[5];
    const float* m1  = (const float*)d_in[6];
    const float* v1  = (const float*)d_in[7];
    const float* W2  = (const float*)d_in[8];
    const float* b2  = (const float*)d_in[9];
    const float* g2  = (const float*)d_in[10];
    const float* be2 = (const float*)d_in[11];
    const float* m2  = (const float*)d_in[12];
    const float* v2  = (const float*)d_in[13];

    const int N = in_sizes[0] / 512;   // 50000
    const int E = in_sizes[1] / 2;     // 800000
    const int* src = ei;
    const int* dst = ei + E;
    const int CSR_CAP = E + 8 * N;     // int2 entries
    const int NB = (N + 1023) / 1024;  // 49

    char* ws = (char*)d_ws;
    size_t off = 0;
    _Float16* hAh = (_Float16*)(ws + off); off += align_up((size_t)N * 128 * 2);
    _Float16* h0h = (_Float16*)(ws + off); off += align_up((size_t)N * 128 * 2);
    _Float16* p0  = (_Float16*)(ws + off); off += align_up((size_t)N * 128 * 2);
    _Float16* p1  = (_Float16*)(ws + off); off += align_up((size_t)N * 128 * 2);
    int*    deg  = (int*)(ws + off);    off += align_up((size_t)N * 4);
    float*  dinv = (float*)(ws + off);  off += align_up((size_t)N * 4);
    int*    offs = (int*)(ws + off);    off += align_up((size_t)(N + 1) * 4);
    int*    curs = (int*)(ws + off);    off += align_up((size_t)N * 4);
    int*    bsum = (int*)(ws + off);    off += align_up((size_t)256 * 4);
    int2*   csr  = (int2*)(ws + off);   off += align_up((size_t)CSR_CAP * 8);
    _Float16* w1s = (_Float16*)(ws + off); off += align_up((size_t)512 * 128 * 2);
    _Float16* w2s = (_Float16*)(ws + off); off += align_up((size_t)128 * 128 * 2);

    // --- graph preprocessing ---
    hipMemsetAsync(deg, 0, (size_t)N * 4, stream);
    count_deg<<<(E + 255) / 256, 256, 0, stream>>>(dst, E, deg);
    scan_block_sums<<<NB, 256, 0, stream>>>(deg, bsum, N);
    scan_offsets<<<NB, 256, 0, stream>>>(deg, bsum, offs, curs, dinv, N, NB);
    scatter_csr<<<(E + 255) / 256, 256, 0, stream>>>(src, dst, E, dinv, curs, csr);
    fill_self_pad<<<(N + 255) / 256, 256, 0, stream>>>(offs, deg, dinv, csr, N);

    // --- weights -> staging-interleaved fp16 ---
    convert_wstg<<<(512 * 128 + 255) / 256, 256, 0, stream>>>(W1, w1s, 512);
    convert_wstg<<<(128 * 128 + 255) / 256, 256, 0, stream>>>(W2, w2s, 128);

    // --- MLP: hAh = BN1(relu(x@W1+b1)) fp16; h0h = BN2(hAh@W2+b2) fp16 ---
    gemm_stage_bn<false, true><<<(N + 63) / 64, 256, 0, stream>>>(
        x, w1s, b1, g1, be1, m1, v1, hAh, N, 512, 1);
    gemm_stage_bn<true, true><<<(N + 63) / 64, 256, 0, stream>>>(
        hAh, w2s, b2, g2, be2, m2, v2, h0h, N, 128, 0);

    // --- 10 propagation steps (fp16 ping-pong); step 10 writes fp32 d_out ---
    const _Float16* cur = h0h;
    for (int k = 0; k < 10; ++k) {
        _Float16* nxt = (k & 1) ? p1 : p0;
        float* fo = (k == 9) ? (float*)d_out : nullptr;
        appnp_step<<<NWAVES / 4, 256, 0, stream>>>(
            cur, h0h, offs, csr, nxt, fo, N);
        cur = nxt;
    }

    (void)n_in; (void)out_size; (void)ws_size;
}